// Round 7
// baseline (1127.757 us; speedup 1.0000x reference)
//
#include <hip/hip_runtime.h>

#define NN 50000
#define NE 800000
#define HD 64
#define NL 2
#define NT_N (NN / 16)   // 3125 dst-tiles
#define NCH 196          // scan chunks: 196*256 = 50176 >= NN

typedef __attribute__((ext_vector_type(4))) float f32x4;
typedef __attribute__((ext_vector_type(8))) short s16x8;

// ---- d_ws layout (float element offsets) ----
#define FLAG_OFF 0
#define WB_OFF   16
#define EMB_O 0
#define EW1_O 6400
#define EB1_O 22912
#define EW2_O 23040
#define EB2_O 31232
#define HW1_O 31360
#define HB1_O 47744
#define HW2_O 47872
#define HB2_O 56064
#define XW1_O 56192
#define XB1_O 64384
#define XW2_O 64512
#define XB2_O 64640
#define X0_OFF   (WB_OFF + 64656)          // fp32 x ping, padded [NN][4]
#define X1_OFF   (X0_OFF + NN * 4)         // fp32 x pong
#define HBF0_OFF (X1_OFF + NN * 4)         // ushort[NN*64] ping
#define HBF1_OFF (HBF0_OFF + NN * 32)      // ushort[NN*64] pong
#define CNT_OFF  (HBF1_OFF + NN * 32)
#define CSUM_OFF (CNT_OFF + NCH * 256)
#define INCL_OFF (CSUM_OFF + 256)
#define PAIR_OFF (INCL_OFF + NCH * 256)    // int2[NE]

#define ROWP 72
#define MPITCH 68   // macc row pitch (fp32): 16B-aligned, rotates banks by 4

__device__ __forceinline__ float bf2f(unsigned short u) {
    return __uint_as_float(((unsigned int)u) << 16);
}
__device__ __forceinline__ unsigned short f2bf(float f) {      // RNE
    unsigned int i = __float_as_uint(f);
    i += 0x7fffu + ((i >> 16) & 1u);
    return (unsigned short)(i >> 16);
}
__device__ __forceinline__ unsigned short f2bf_t(float f) {    // trunc (GEMM temps)
    return (unsigned short)(__float_as_uint(f) >> 16);
}
__device__ __forceinline__ float silu(float v) {
    const float e = __expf(-v);
    return v * __builtin_amdgcn_rcpf(1.0f + e);
}
__device__ __forceinline__ float ldf(const void* p, int i, int bf) {
    return bf ? bf2f(((const unsigned short*)p)[i]) : ((const float*)p)[i];
}

// -------------------------------------------------------------- detect ------
__global__ void detect_kernel(const unsigned short* __restrict__ pos, int* __restrict__ flag) {
    const int lane = threadIdx.x;
    const float v = bf2f(pos[2 * lane]);
    const float a = fabsf(v);
    const int ok = (a >= 1e-6f && a <= 1e6f) ? 1 : 0;
    const unsigned long long m = __ballot(ok);
    if (lane == 0) *flag = (__popcll(m) >= 32) ? 1 : 0;
}

// -------------------------------------------------------------- convert -----
__global__ __launch_bounds__(256) void convert_kernel(
    const void* pos, const void* emb,
    const void* ew1, const void* eb1, const void* ew2, const void* eb2,
    const void* hw1, const void* hb1, const void* hw2, const void* hb2,
    const void* xw1, const void* xb1, const void* xw2, const void* xb2,
    float* __restrict__ wbuf, float* __restrict__ x0, const int* __restrict__ flag)
{
    const int bf = *flag;
    const int tid = blockIdx.x * blockDim.x + threadIdx.x;
    const int stride = gridDim.x * blockDim.x;
    for (int n = tid; n < NN; n += stride) {
        x0[n * 4 + 0] = ldf(pos, n * 3 + 0, bf);
        x0[n * 4 + 1] = ldf(pos, n * 3 + 1, bf);
        x0[n * 4 + 2] = ldf(pos, n * 3 + 2, bf);
        x0[n * 4 + 3] = 0.f;
    }
    for (int i = tid; i < 6400; i += stride) wbuf[EMB_O + i] = ldf(emb, i, bf);
    for (int i = tid; i < 16512; i += stride) wbuf[EW1_O + i] = ldf(ew1, i, bf);
    for (int i = tid; i < 128; i += stride) wbuf[EB1_O + i] = ldf(eb1, i, bf);
    for (int i = tid; i < 8192; i += stride) wbuf[EW2_O + i] = ldf(ew2, i, bf);
    for (int i = tid; i < 128; i += stride) wbuf[EB2_O + i] = ldf(eb2, i, bf);
    for (int i = tid; i < 16384; i += stride) wbuf[HW1_O + i] = ldf(hw1, i, bf);
    for (int i = tid; i < 128; i += stride) wbuf[HB1_O + i] = ldf(hb1, i, bf);
    for (int i = tid; i < 8192; i += stride) wbuf[HW2_O + i] = ldf(hw2, i, bf);
    for (int i = tid; i < 128; i += stride) wbuf[HB2_O + i] = ldf(hb2, i, bf);
    for (int i = tid; i < 8192; i += stride) wbuf[XW1_O + i] = ldf(xw1, i, bf);
    for (int i = tid; i < 128; i += stride) wbuf[XB1_O + i] = ldf(xb1, i, bf);
    for (int i = tid; i < 128; i += stride) wbuf[XW2_O + i] = ldf(xw2, i, bf);
    for (int i = tid; i < 2; i += stride) wbuf[XB2_O + i] = ldf(xb2, i, bf);
}

// -------------------------------------------------------------- init h ------
__global__ __launch_bounds__(256) void init_h_kernel(
    const int* __restrict__ an, const float* __restrict__ embf,
    unsigned short* __restrict__ h_bf)
{
    const int stride = gridDim.x * blockDim.x;
    for (int i = blockIdx.x * blockDim.x + threadIdx.x; i < NN * HD; i += stride) {
        int a = an[i >> 6];
        a = (a < 0) ? 0 : (a > 99 ? 99 : a);
        h_bf[i] = f2bf(embf[a * HD + (i & 63)]);
    }
}

// -------------------------------------------------------------- sort --------
__global__ __launch_bounds__(256) void hist_kernel(const int* __restrict__ ei, int* __restrict__ cnt) {
    const int stride = gridDim.x * blockDim.x;
    for (int e = blockIdx.x * blockDim.x + threadIdx.x; e < NE; e += stride) {
        int d = ei[NE + e];
        d = (d < 0) ? 0 : (d >= NN ? NN - 1 : d);
        atomicAdd(&cnt[d], 1);
    }
}

__global__ __launch_bounds__(256) void scan1_kernel(
    const int* __restrict__ cnt, int* __restrict__ incl, int* __restrict__ csum)
{
    __shared__ int s[256];
    const int t = threadIdx.x, b = blockIdx.x, i = b * 256 + t;
    s[t] = cnt[i];
    __syncthreads();
#pragma unroll
    for (int o = 1; o < 256; o <<= 1) {
        const int u = (t >= o) ? s[t - o] : 0;
        __syncthreads();
        s[t] += u;
        __syncthreads();
    }
    incl[i] = s[t];
    if (t == 255) csum[b] = s[255];
}

__global__ void scan2_kernel(int* __restrict__ csum) {
    __shared__ int s[256];
    const int t = threadIdx.x;
    s[t] = (t < NCH) ? csum[t] : 0;
    __syncthreads();
#pragma unroll
    for (int o = 1; o < 256; o <<= 1) {
        const int u = (t >= o) ? s[t - o] : 0;
        __syncthreads();
        s[t] += u;
        __syncthreads();
    }
    if (t < NCH) csum[t] = s[t];
}

// incl += chunk offset (finalize global inclusive prefix); cur = excl prefix
__global__ __launch_bounds__(256) void scan3_kernel(
    int* __restrict__ cnt, int* __restrict__ incl, const int* __restrict__ csum)
{
    const int t = threadIdx.x, b = blockIdx.x, i = b * 256 + t;
    const int off = (b > 0) ? csum[b - 1] : 0;
    const int inc = incl[i] + off;
    incl[i] = inc;
    cnt[i] = inc - cnt[i];   // exclusive prefix -> scatter cursor
}

__global__ __launch_bounds__(256) void scatter_kernel(
    const int* __restrict__ ei, int* __restrict__ cur, int2* __restrict__ pair)
{
    const int stride = gridDim.x * blockDim.x;
    for (int e = blockIdx.x * blockDim.x + threadIdx.x; e < NE; e += stride) {
        int s = ei[e];
        int d = ei[NE + e];
        s = (s < 0) ? 0 : (s >= NN ? NN - 1 : s);
        d = (d < 0) ? 0 : (d >= NN ? NN - 1 : d);
        const int p = atomicAdd(&cur[d], 1);
        pair[p] = make_int2(s, d);
    }
}

// -------------------------------------------------------------- fused layer -
// One block = 16 dst nodes + all their (sorted) edges. m aggregated in LDS
// fp32; node MLP fused after a block-local barrier. h/x double-buffered
// across layers (kernel boundary = global barrier).
__global__ __launch_bounds__(256, 3) void fused_layer_kernel(
    const unsigned short* __restrict__ h_in, unsigned short* __restrict__ h_out,
    const float* __restrict__ x_in, float* __restrict__ x_out,
    const int2* __restrict__ pair, const int* __restrict__ incl,
    const float* __restrict__ ew1, const float* __restrict__ eb1,
    const float* __restrict__ ew2, const float* __restrict__ eb2,
    const float* __restrict__ xw1, const float* __restrict__ xb1,
    const float* __restrict__ xw2, const float* __restrict__ xb2,
    const float* __restrict__ hw1, const float* __restrict__ hb1,
    const float* __restrict__ hw2, const float* __restrict__ hb2,
    void* __restrict__ outv, const int* __restrict__ flag)
{
    __shared__ unsigned short s_ew1p[4 * 4 * 64 * 8];  // 16 KB
    __shared__ unsigned short s_hw1p[4 * 4 * 64 * 8];  // 16 KB
    __shared__ unsigned short s_act[4][16 * ROWP];     // 9 KB (per-wave)
    __shared__ float s_macc[16 * MPITCH];              // 4.25 KB fp32 m-acc
    __shared__ float s_xacc[16 * 4];                   // 256 B
    __shared__ float s_xd[4][16][4];                   // 1 KB

    const int tid = threadIdx.x;
    const int lane = tid & 63;
    const int wid = tid >> 6;
    const int l15 = lane & 15;
    const int q = lane >> 4;
    const int t = blockIdx.x;
    const int n0 = t * 16;

    // stage packed B-frags (value = W[k][n], k=kc*32+(ln>>4)*8+j, n=nt*16+(ln&15))
    for (int p = tid; p < 4 * 4 * 64 * 8; p += 256) {
        const int j = p & 7, ln = (p >> 3) & 63, nt = (p >> 9) & 3, kc = p >> 11;
        const int k = kc * 32 + (ln >> 4) * 8 + j, n = nt * 16 + (ln & 15);
        s_ew1p[p] = f2bf(ew1[k * 64 + n]);
        s_hw1p[p] = f2bf(hw1[k * 64 + n]);
    }
    for (int i = tid; i < 16 * MPITCH; i += 256) s_macc[i] = 0.f;
    if (tid < 64) s_xacc[tid] = 0.f;

    // register-held B-frags for phi_e L2 and phi_x L1; node L2 slice
    s16x8 bw2[2][4], bxw1[2][4];
#pragma unroll
    for (int kc = 0; kc < 2; ++kc)
#pragma unroll
        for (int nt = 0; nt < 4; ++nt)
#pragma unroll
            for (int j = 0; j < 8; ++j) {
                const int wi = (kc * 32 + q * 8 + j) * 64 + nt * 16 + l15;
                bw2[kc][nt][j] = (short)f2bf(ew2[wi]);
                bxw1[kc][nt][j] = (short)f2bf(xw1[wi]);
            }
    const int ncol = wid * 16 + l15;   // node-phase column for this wave
    s16x8 bhw2[2];
#pragma unroll
    for (int kc = 0; kc < 2; ++kc)
#pragma unroll
        for (int j = 0; j < 8; ++j)
            bhw2[kc][j] = (short)f2bf(hw2[(kc * 32 + q * 8 + j) * 64 + ncol]);

    float b1v[4], b2v[4], xb1v[4], xw2v[4], wrv[4];
#pragma unroll
    for (int nt = 0; nt < 4; ++nt) {
        b1v[nt] = eb1[nt * 16 + l15];
        b2v[nt] = eb2[nt * 16 + l15];
        xb1v[nt] = xb1[nt * 16 + l15];
        xw2v[nt] = xw2[nt * 16 + l15];
        wrv[nt] = ew1[128 * 64 + nt * 16 + l15];
    }
    const float xb2v = xb2[0];
    const float hb1v = hb1[ncol], hb2v = hb2[ncol];

    __syncthreads();

    unsigned short* act = s_act[wid];
    float (*xd)[4] = s_xd[wid];

    const int e_start = (t == 0) ? 0 : incl[n0 - 1];
    const int e_end = incl[n0 + 15];

    // ================= edge phase: 16-edge chunks round-robin over waves ====
    for (int ce = e_start + wid * 16; ce < e_end; ce += 64) {
        const int nv = e_end - ce;                   // valid rows (>=1)
        const int idx = ce + l15;
        const int2 epr = pair[(idx < e_end) ? idx : (e_end - 1)];
        const int sidx = epr.x, didx = epr.y;
        const f32x4 xs = *(const f32x4*)&x_in[sidx * 4];
        const f32x4 xdv = *(const f32x4*)&x_in[didx * 4];
        const float ax = xs[0] - xdv[0];
        const float ay = xs[1] - xdv[1];
        const float az = xs[2] - xdv[2];
        const float rme = sqrtf(ax * ax + ay * ay + az * az);
        if (lane < 16) { xd[lane][0] = ax; xd[lane][1] = ay; xd[lane][2] = az; }

        const s16x8 a_hd0 = *(const s16x8*)&h_in[didx * 64 + q * 8];
        const s16x8 a_hd1 = *(const s16x8*)&h_in[didx * 64 + 32 + q * 8];
        const s16x8 a_hs0 = *(const s16x8*)&h_in[sidx * 64 + q * 8];
        const s16x8 a_hs1 = *(const s16x8*)&h_in[sidx * 64 + 32 + q * 8];

        // ---- phi_e layer 1 ----
        f32x4 acc[4];
#pragma unroll
        for (int nt = 0; nt < 4; ++nt) acc[nt] = (f32x4){0.f, 0.f, 0.f, 0.f};
#pragma unroll
        for (int kc = 0; kc < 4; ++kc) {
            const s16x8 a = (kc == 0) ? a_hd0 : (kc == 1) ? a_hd1 : (kc == 2) ? a_hs0 : a_hs1;
#pragma unroll
            for (int nt = 0; nt < 4; ++nt) {
                const s16x8 b = *(const s16x8*)&s_ew1p[((kc * 4 + nt) * 64 + lane) * 8];
                acc[nt] = __builtin_amdgcn_mfma_f32_16x16x32_bf16(a, b, acc[nt], 0, 0, 0);
            }
        }
        float rv[4];
        int dsh[4], vr[4];
#pragma unroll
        for (int r = 0; r < 4; ++r) {
            rv[r] = __shfl(rme, q * 4 + r, 64);
            dsh[r] = __shfl(didx, q * 4 + r, 64) - n0;
            vr[r] = (q * 4 + r) < nv;
        }
#pragma unroll
        for (int nt = 0; nt < 4; ++nt)
#pragma unroll
            for (int r = 0; r < 4; ++r) {
                const float v = silu(acc[nt][r] + b1v[nt] + rv[r] * wrv[nt]);
                act[(q * 4 + r) * ROWP + nt * 16 + l15] = f2bf_t(v);
            }

        // ---- phi_e layer 2 -> m: LDS fp32 accumulate + bf16 act for phi_x --
        f32x4 acc2[4];
#pragma unroll
        for (int nt = 0; nt < 4; ++nt) acc2[nt] = (f32x4){0.f, 0.f, 0.f, 0.f};
#pragma unroll
        for (int kc = 0; kc < 2; ++kc) {
            const s16x8 a = *(const s16x8*)&act[l15 * ROWP + kc * 32 + q * 8];
#pragma unroll
            for (int nt = 0; nt < 4; ++nt)
                acc2[nt] = __builtin_amdgcn_mfma_f32_16x16x32_bf16(a, bw2[kc][nt], acc2[nt], 0, 0, 0);
        }
#pragma unroll
        for (int nt = 0; nt < 4; ++nt)
#pragma unroll
            for (int r = 0; r < 4; ++r) {
                const float v = silu(acc2[nt][r] + b2v[nt]);
                act[(q * 4 + r) * ROWP + nt * 16 + l15] = f2bf_t(v);
                if (vr[r]) atomicAdd(&s_macc[dsh[r] * MPITCH + nt * 16 + l15], v);
            }

        // ---- phi_x layer 1 ----
        f32x4 xacc[4];
#pragma unroll
        for (int nt = 0; nt < 4; ++nt) xacc[nt] = (f32x4){0.f, 0.f, 0.f, 0.f};
#pragma unroll
        for (int kc = 0; kc < 2; ++kc) {
            const s16x8 a = *(const s16x8*)&act[l15 * ROWP + kc * 32 + q * 8];
#pragma unroll
            for (int nt = 0; nt < 4; ++nt)
                xacc[nt] = __builtin_amdgcn_mfma_f32_16x16x32_bf16(a, bxw1[kc][nt], xacc[nt], 0, 0, 0);
        }
        // ---- phi_x layer 2: per-edge scalar W, LDS fp32 x-accumulate ------
        float ssum[4];
#pragma unroll
        for (int r = 0; r < 4; ++r) {
            float s = 0.f;
#pragma unroll
            for (int nt = 0; nt < 4; ++nt)
                s += silu(xacc[nt][r] + xb1v[nt]) * xw2v[nt];
            ssum[r] = s;
        }
#pragma unroll
        for (int off = 1; off < 16; off <<= 1)
#pragma unroll
            for (int r = 0; r < 4; ++r) ssum[r] += __shfl_xor(ssum[r], off, 64);
        if (l15 < 3) {
#pragma unroll
            for (int r = 0; r < 4; ++r) {
                if (vr[r]) {
                    const float W = ssum[r] + xb2v;
                    atomicAdd(&s_xacc[dsh[r] * 4 + l15], W * xd[q * 4 + r][l15]);
                }
            }
        }
    }
    __syncthreads();

    // ================= node phase: wave wid owns cols [wid*16, wid*16+16) ===
    const int nrow = n0 + l15;
    const s16x8 ah0 = *(const s16x8*)&h_in[nrow * 64 + q * 8];
    const s16x8 ah1 = *(const s16x8*)&h_in[nrow * 64 + 32 + q * 8];
    const f32x4 mm0 = *(const f32x4*)&s_macc[l15 * MPITCH + q * 8];
    const f32x4 mm1 = *(const f32x4*)&s_macc[l15 * MPITCH + q * 8 + 4];
    const f32x4 mm2 = *(const f32x4*)&s_macc[l15 * MPITCH + 32 + q * 8];
    const f32x4 mm3 = *(const f32x4*)&s_macc[l15 * MPITCH + 32 + q * 8 + 4];
    s16x8 am0, am1;
#pragma unroll
    for (int j = 0; j < 4; ++j) {
        am0[j] = (short)f2bf(mm0[j]); am0[4 + j] = (short)f2bf(mm1[j]);
        am1[j] = (short)f2bf(mm2[j]); am1[4 + j] = (short)f2bf(mm3[j]);
    }

    f32x4 nacc = (f32x4){0.f, 0.f, 0.f, 0.f};
#pragma unroll
    for (int kc = 0; kc < 4; ++kc) {
        const s16x8 a = (kc == 0) ? ah0 : (kc == 1) ? ah1 : (kc == 2) ? am0 : am1;
        const s16x8 b = *(const s16x8*)&s_hw1p[((kc * 4 + wid) * 64 + lane) * 8];
        nacc = __builtin_amdgcn_mfma_f32_16x16x32_bf16(a, b, nacc, 0, 0, 0);
    }
#pragma unroll
    for (int r = 0; r < 4; ++r)
        s_act[0][(q * 4 + r) * ROWP + ncol] = f2bf_t(silu(nacc[r] + hb1v));
    __syncthreads();

    f32x4 nacc2 = (f32x4){0.f, 0.f, 0.f, 0.f};
#pragma unroll
    for (int kc = 0; kc < 2; ++kc) {
        const s16x8 a = *(const s16x8*)&s_act[0][l15 * ROWP + kc * 32 + q * 8];
        nacc2 = __builtin_amdgcn_mfma_f32_16x16x32_bf16(a, bhw2[kc], nacc2, 0, 0, 0);
    }
    const int bfl = flag ? *flag : 1;
#pragma unroll
    for (int r = 0; r < 4; ++r) {
        const int row = n0 + q * 4 + r;
        const float hn = bf2f(h_in[row * 64 + ncol]) + nacc2[r] + hb2v;
        h_out[row * 64 + ncol] = f2bf(hn);
        if (outv) {
            if (bfl) ((unsigned short*)outv)[row * 64 + ncol] = f2bf(hn);
            else ((float*)outv)[row * 64 + ncol] = hn;
        }
    }
    if (tid < 48) {
        const int n = tid / 3, c = tid - n * 3;
        const float xn = x_in[(n0 + n) * 4 + c] + s_xacc[n * 4 + c];
        x_out[(n0 + n) * 4 + c] = xn;
        if (outv) {
            if (bfl) ((unsigned short*)outv)[NN * HD + (n0 + n) * 3 + c] = f2bf(xn);
            else ((float*)outv)[NN * HD + (n0 + n) * 3 + c] = xn;
        }
    } else if (tid < 64) {
        x_out[(n0 + (tid - 48)) * 4 + 3] = 0.f;
    }
}

// -------------------------------------------------------------- launch ------
extern "C" void kernel_launch(void* const* d_in, const int* in_sizes, int n_in,
                              void* d_out, int out_size, void* d_ws, size_t ws_size,
                              hipStream_t stream) {
    const int* an = (const int*)d_in[0];
    const void* pos = d_in[1];
    const int* ei = (const int*)d_in[2];

    int wi = 4;
    if (n_in > 4 && in_sizes[4] == 6400) wi = 4;
    else if (n_in > 3 && in_sizes[3] == 6400) wi = 3;
    const void* emb = d_in[wi];
    const void* e_w1 = d_in[wi + 1];
    const void* e_b1 = d_in[wi + 2];
    const void* e_w2 = d_in[wi + 3];
    const void* e_b2 = d_in[wi + 4];
    const void* h_w1 = d_in[wi + 5];
    const void* h_b1 = d_in[wi + 6];
    const void* h_w2 = d_in[wi + 7];
    const void* h_b2 = d_in[wi + 8];
    const void* x_w1 = d_in[wi + 9];
    const void* x_b1 = d_in[wi + 10];
    const void* x_w2 = d_in[wi + 11];
    const void* x_b2 = d_in[wi + 12];

    float* ws = (float*)d_ws;
    int* flag = (int*)(ws + FLAG_OFF);
    float* wbuf = ws + WB_OFF;
    float* x0 = ws + X0_OFF;
    float* x1 = ws + X1_OFF;
    unsigned short* h0 = (unsigned short*)(ws + HBF0_OFF);
    unsigned short* h1 = (unsigned short*)(ws + HBF1_OFF);
    int* cnt = (int*)(ws + CNT_OFF);
    int* csum = (int*)(ws + CSUM_OFF);
    int* incl = (int*)(ws + INCL_OFF);
    int2* pair = (int2*)(ws + PAIR_OFF);

    detect_kernel<<<1, 64, 0, stream>>>((const unsigned short*)pos, flag);
    convert_kernel<<<256, 256, 0, stream>>>(pos, emb,
        e_w1, e_b1, e_w2, e_b2, h_w1, h_b1, h_w2, h_b2,
        x_w1, x_b1, x_w2, x_b2, wbuf, x0, flag);
    init_h_kernel<<<784, 256, 0, stream>>>(an, wbuf + EMB_O, h0);

    hipMemsetAsync(cnt, 0, NCH * 256 * sizeof(int), stream);
    hist_kernel<<<512, 256, 0, stream>>>(ei, cnt);
    scan1_kernel<<<NCH, 256, 0, stream>>>(cnt, incl, csum);
    scan2_kernel<<<1, 256, 0, stream>>>(csum);
    scan3_kernel<<<NCH, 256, 0, stream>>>(cnt, incl, csum);
    scatter_kernel<<<512, 256, 0, stream>>>(ei, cnt, pair);

    for (int l = 0; l < NL; ++l) {
        const unsigned short* hi = (l == 0) ? h0 : h1;
        unsigned short* ho = (l == 0) ? h1 : h0;
        const float* xi = (l == 0) ? x0 : x1;
        float* xo = (l == 0) ? x1 : x0;
        void* out_p = (l == NL - 1) ? d_out : nullptr;

        fused_layer_kernel<<<NT_N, 256, 0, stream>>>(
            hi, ho, xi, xo, pair, incl,
            wbuf + EW1_O + l * 129 * 64, wbuf + EB1_O + l * 64,
            wbuf + EW2_O + l * 64 * 64, wbuf + EB2_O + l * 64,
            wbuf + XW1_O + l * 64 * 64, wbuf + XB1_O + l * 64,
            wbuf + XW2_O + l * 64, wbuf + XB2_O + l,
            wbuf + HW1_O + l * 128 * 64, wbuf + HB1_O + l * 64,
            wbuf + HW2_O + l * 64 * 64, wbuf + HB2_O + l * 64,
            out_p, flag);
    }
}

// Round 8
// 472.600 us; speedup vs baseline: 2.3863x; 2.3863x over previous
//
#include <hip/hip_runtime.h>

#define NN 50000
#define NE 800000
#define HD 64
#define NL 2
#define NT_E (NE / 16)   // 50000 edge tiles
#define NT_N (NN / 16)   // 3125 node tiles
#define NCH 196          // scan chunks: 196*256 = 50176 >= NN+1

typedef __attribute__((ext_vector_type(4))) float f32x4;
typedef __attribute__((ext_vector_type(8))) short s16x8;

// ---- d_ws layout (float element offsets) ----
#define FLAG_OFF 0
#define WB_OFF   16
#define EMB_O 0
#define EW1_O 6400
#define EB1_O 22912
#define EW2_O 23040
#define EB2_O 31232
#define HW1_O 31360
#define HB1_O 47744
#define HW2_O 47872
#define HB2_O 56064
#define XW1_O 56192
#define XB1_O 64384
#define XW2_O 64512
#define XB2_O 64640
#define X_OFF    (WB_OFF + 64656)              // fp32 x, padded [NN][4]
#define MAGG_OFF (X_OFF + NN * 4)
#define XAGG_OFF (MAGG_OFF + NN * HD)
#define HBF_OFF  (XAGG_OFF + NN * 3)           // ushort[NN*64]
#define CNT_OFF  (HBF_OFF + NN * 32)
#define CSUM_OFF (CNT_OFF + NCH * 256)
#define INCL_OFF (CSUM_OFF + 256)
#define PAIR_OFF (INCL_OFF + NCH * 256)        // int2[NE]

#define ROWP 72

__device__ __forceinline__ float bf2f(unsigned short u) {
    return __uint_as_float(((unsigned int)u) << 16);
}
__device__ __forceinline__ unsigned short f2bf(float f) {      // RNE
    unsigned int i = __float_as_uint(f);
    i += 0x7fffu + ((i >> 16) & 1u);
    return (unsigned short)(i >> 16);
}
__device__ __forceinline__ unsigned short f2bf_t(float f) {    // trunc (GEMM temps)
    return (unsigned short)(__float_as_uint(f) >> 16);
}
__device__ __forceinline__ float silu(float v) {               // no div sequence
    const float e = __expf(-v);
    return v * __builtin_amdgcn_rcpf(1.0f + e);
}
__device__ __forceinline__ float ldf(const void* p, int i, int bf) {
    return bf ? bf2f(((const unsigned short*)p)[i]) : ((const float*)p)[i];
}

// -------------------------------------------------------------- detect ------
__global__ void detect_kernel(const unsigned short* __restrict__ pos, int* __restrict__ flag) {
    const int lane = threadIdx.x;
    const float v = bf2f(pos[2 * lane]);
    const float a = fabsf(v);
    const int ok = (a >= 1e-6f && a <= 1e6f) ? 1 : 0;
    const unsigned long long m = __ballot(ok);
    if (lane == 0) *flag = (__popcll(m) >= 32) ? 1 : 0;
}

// -------------------------------------------------------------- convert -----
__global__ __launch_bounds__(256) void convert_kernel(
    const void* pos, const void* emb,
    const void* ew1, const void* eb1, const void* ew2, const void* eb2,
    const void* hw1, const void* hb1, const void* hw2, const void* hb2,
    const void* xw1, const void* xb1, const void* xw2, const void* xb2,
    float* __restrict__ wbuf, float* __restrict__ x, const int* __restrict__ flag)
{
    const int bf = *flag;
    const int tid = blockIdx.x * blockDim.x + threadIdx.x;
    const int stride = gridDim.x * blockDim.x;
    for (int n = tid; n < NN; n += stride) {
        x[n * 4 + 0] = ldf(pos, n * 3 + 0, bf);
        x[n * 4 + 1] = ldf(pos, n * 3 + 1, bf);
        x[n * 4 + 2] = ldf(pos, n * 3 + 2, bf);
        x[n * 4 + 3] = 0.f;
    }
    for (int i = tid; i < 6400; i += stride) wbuf[EMB_O + i] = ldf(emb, i, bf);
    for (int i = tid; i < 16512; i += stride) wbuf[EW1_O + i] = ldf(ew1, i, bf);
    for (int i = tid; i < 128; i += stride) wbuf[EB1_O + i] = ldf(eb1, i, bf);
    for (int i = tid; i < 8192; i += stride) wbuf[EW2_O + i] = ldf(ew2, i, bf);
    for (int i = tid; i < 128; i += stride) wbuf[EB2_O + i] = ldf(eb2, i, bf);
    for (int i = tid; i < 16384; i += stride) wbuf[HW1_O + i] = ldf(hw1, i, bf);
    for (int i = tid; i < 128; i += stride) wbuf[HB1_O + i] = ldf(hb1, i, bf);
    for (int i = tid; i < 8192; i += stride) wbuf[HW2_O + i] = ldf(hw2, i, bf);
    for (int i = tid; i < 128; i += stride) wbuf[HB2_O + i] = ldf(hb2, i, bf);
    for (int i = tid; i < 8192; i += stride) wbuf[XW1_O + i] = ldf(xw1, i, bf);
    for (int i = tid; i < 128; i += stride) wbuf[XB1_O + i] = ldf(xb1, i, bf);
    for (int i = tid; i < 128; i += stride) wbuf[XW2_O + i] = ldf(xw2, i, bf);
    for (int i = tid; i < 2; i += stride) wbuf[XB2_O + i] = ldf(xb2, i, bf);
}

// -------------------------------------------------------------- init h ------
__global__ __launch_bounds__(256) void init_h_kernel(
    const int* __restrict__ an, const float* __restrict__ embf,
    unsigned short* __restrict__ h_bf)
{
    const int stride = gridDim.x * blockDim.x;
    for (int i = blockIdx.x * blockDim.x + threadIdx.x; i < NN * HD; i += stride) {
        int a = an[i >> 6];
        a = (a < 0) ? 0 : (a > 99 ? 99 : a);
        h_bf[i] = f2bf(embf[a * HD + (i & 63)]);
    }
}

// -------------------------------------------------------------- sort --------
__global__ __launch_bounds__(256) void hist_kernel(const int* __restrict__ ei, int* __restrict__ cnt) {
    const int stride = gridDim.x * blockDim.x;
    for (int e = blockIdx.x * blockDim.x + threadIdx.x; e < NE; e += stride) {
        int d = ei[NE + e];
        d = (d < 0) ? 0 : (d >= NN ? NN - 1 : d);
        atomicAdd(&cnt[d], 1);
    }
}

__global__ __launch_bounds__(256) void scan1_kernel(
    const int* __restrict__ cnt, int* __restrict__ incl, int* __restrict__ csum)
{
    __shared__ int s[256];
    const int t = threadIdx.x, b = blockIdx.x, i = b * 256 + t;
    s[t] = cnt[i];
    __syncthreads();
#pragma unroll
    for (int o = 1; o < 256; o <<= 1) {
        const int u = (t >= o) ? s[t - o] : 0;
        __syncthreads();
        s[t] += u;
        __syncthreads();
    }
    incl[i] = s[t];
    if (t == 255) csum[b] = s[255];
}

__global__ void scan2_kernel(int* __restrict__ csum) {
    __shared__ int s[256];
    const int t = threadIdx.x;
    s[t] = (t < NCH) ? csum[t] : 0;
    __syncthreads();
#pragma unroll
    for (int o = 1; o < 256; o <<= 1) {
        const int u = (t >= o) ? s[t - o] : 0;
        __syncthreads();
        s[t] += u;
        __syncthreads();
    }
    if (t < NCH) csum[t] = s[t];
}

__global__ __launch_bounds__(256) void scan3_kernel(
    int* __restrict__ cnt, const int* __restrict__ incl, const int* __restrict__ csum)
{
    const int t = threadIdx.x, b = blockIdx.x, i = b * 256 + t;
    const int off = (b > 0) ? csum[b - 1] : 0;
    cnt[i] = incl[i] - cnt[i] + off;
}

__global__ __launch_bounds__(256) void scatter_kernel(
    const int* __restrict__ ei, int* __restrict__ cur, int2* __restrict__ pair)
{
    const int stride = gridDim.x * blockDim.x;
    for (int e = blockIdx.x * blockDim.x + threadIdx.x; e < NE; e += stride) {
        int s = ei[e];
        int d = ei[NE + e];
        s = (s < 0) ? 0 : (s >= NN ? NN - 1 : s);
        d = (d < 0) ? 0 : (d >= NN ? NN - 1 : d);
        const int p = atomicAdd(&cur[d], 1);
        pair[p] = make_int2(s, d);
    }
}

// -------------------------------------------------------------- edge MFMA ---
// One wave = 16 dst-sorted edges; w2 AND xw1 B-frags in registers (2 sets,
// no spill per R5/R6 evidence); fast silu; trunc temps except m (RNE).
// LDS ~26.5 KB; __launch_bounds__(256,4) caps VGPR at 128.
__global__ __launch_bounds__(256, 4) void edge_mfma_kernel(
    const unsigned short* __restrict__ h_bf, const float* __restrict__ x,
    const int2* __restrict__ pair,
    const float* __restrict__ w1, const float* __restrict__ b1,
    const float* __restrict__ b2,
    const float* __restrict__ w2,
    const float* __restrict__ xw1, const float* __restrict__ xb1,
    const float* __restrict__ xw2, const float* __restrict__ xb2,
    float* __restrict__ m_agg, float* __restrict__ x_agg)
{
    __shared__ unsigned short s_w1p[4 * 4 * 64 * 8];   // 16 KB
    __shared__ unsigned short s_act[4][16 * ROWP];     // 9 KB
    __shared__ float s_xd[4][16][4];                   // 1 KB
    __shared__ float s_wv[4][16];                      // 256 B

    const int tid = threadIdx.x;
    for (int p = tid; p < 4 * 4 * 64 * 8; p += 256) {
        const int j = p & 7, ln = (p >> 3) & 63, nt = (p >> 9) & 3, kc = p >> 11;
        const int k = kc * 32 + (ln >> 4) * 8 + j, n = nt * 16 + (ln & 15);
        s_w1p[p] = f2bf(w1[k * 64 + n]);
    }
    __syncthreads();

    const int lane = tid & 63;
    const int wid = tid >> 6;
    const int l15 = lane & 15;
    const int q = lane >> 4;

    // register-held B-fragments (loop-invariant): phi_e L2 and phi_x L1
    s16x8 bw2[2][4], bxw1[2][4];
#pragma unroll
    for (int kc = 0; kc < 2; ++kc)
#pragma unroll
        for (int nt = 0; nt < 4; ++nt)
#pragma unroll
            for (int j = 0; j < 8; ++j) {
                const int widx = (kc * 32 + q * 8 + j) * 64 + nt * 16 + l15;
                bw2[kc][nt][j] = (short)f2bf(w2[widx]);
                bxw1[kc][nt][j] = (short)f2bf(xw1[widx]);
            }

    float b1v[4], b2v[4], xb1v[4], xw2v[4], wrv[4];
#pragma unroll
    for (int nt = 0; nt < 4; ++nt) {
        b1v[nt] = b1[nt * 16 + l15];
        b2v[nt] = b2[nt * 16 + l15];
        xb1v[nt] = xb1[nt * 16 + l15];
        xw2v[nt] = xw2[nt * 16 + l15];
        wrv[nt] = w1[128 * 64 + nt * 16 + l15];
    }
    const float xb2v = xb2[0];

    unsigned short* act = s_act[wid];
    float (*xd)[4] = s_xd[wid];
    float* wv = s_wv[wid];

    const int gwave = (blockIdx.x << 2) + wid;
    const int nwaves = gridDim.x << 2;

    for (int t = gwave; t < NT_E; t += nwaves) {
        const int e0 = t * 16;
        const int2 e = pair[e0 + l15];
        const int sidx = e.x, didx = e.y;
        const f32x4 xs = *(const f32x4*)&x[sidx * 4];
        const f32x4 xdv = *(const f32x4*)&x[didx * 4];
        const float ax = xs[0] - xdv[0];
        const float ay = xs[1] - xdv[1];
        const float az = xs[2] - xdv[2];
        const float rme = sqrtf(ax * ax + ay * ay + az * az);
        if (lane < 16) { xd[lane][0] = ax; xd[lane][1] = ay; xd[lane][2] = az; }

        const s16x8 a_hd0 = *(const s16x8*)&h_bf[didx * 64 + q * 8];
        const s16x8 a_hd1 = *(const s16x8*)&h_bf[didx * 64 + 32 + q * 8];
        const s16x8 a_hs0 = *(const s16x8*)&h_bf[sidx * 64 + q * 8];
        const s16x8 a_hs1 = *(const s16x8*)&h_bf[sidx * 64 + 32 + q * 8];

        // ---- phi_e layer 1 ----
        f32x4 acc[4];
#pragma unroll
        for (int nt = 0; nt < 4; ++nt) acc[nt] = (f32x4){0.f, 0.f, 0.f, 0.f};
#pragma unroll
        for (int kc = 0; kc < 4; ++kc) {
            const s16x8 a = (kc == 0) ? a_hd0 : (kc == 1) ? a_hd1 : (kc == 2) ? a_hs0 : a_hs1;
#pragma unroll
            for (int nt = 0; nt < 4; ++nt) {
                const s16x8 b = *(const s16x8*)&s_w1p[((kc * 4 + nt) * 64 + lane) * 8];
                acc[nt] = __builtin_amdgcn_mfma_f32_16x16x32_bf16(a, b, acc[nt], 0, 0, 0);
            }
        }
        float rv[4];
#pragma unroll
        for (int r = 0; r < 4; ++r) rv[r] = __shfl(rme, q * 4 + r, 64);
#pragma unroll
        for (int nt = 0; nt < 4; ++nt)
#pragma unroll
            for (int r = 0; r < 4; ++r) {
                const float v = silu(acc[nt][r] + b1v[nt] + rv[r] * wrv[nt]);
                act[(q * 4 + r) * ROWP + nt * 16 + l15] = f2bf_t(v);
            }

        // ---- phi_e layer 2 (B in registers) -> m (RNE: feeds 16-deep sums) -
        f32x4 acc2[4];
#pragma unroll
        for (int nt = 0; nt < 4; ++nt) acc2[nt] = (f32x4){0.f, 0.f, 0.f, 0.f};
#pragma unroll
        for (int kc = 0; kc < 2; ++kc) {
            const s16x8 a = *(const s16x8*)&act[l15 * ROWP + kc * 32 + q * 8];
#pragma unroll
            for (int nt = 0; nt < 4; ++nt)
                acc2[nt] = __builtin_amdgcn_mfma_f32_16x16x32_bf16(a, bw2[kc][nt], acc2[nt], 0, 0, 0);
        }
#pragma unroll
        for (int nt = 0; nt < 4; ++nt)
#pragma unroll
            for (int r = 0; r < 4; ++r) {
                const float v = silu(acc2[nt][r] + b2v[nt]);
                act[(q * 4 + r) * ROWP + nt * 16 + l15] = f2bf(v);
            }

        // ---- phi_x layer 1 (B in registers) ----
        f32x4 xacc[4];
#pragma unroll
        for (int nt = 0; nt < 4; ++nt) xacc[nt] = (f32x4){0.f, 0.f, 0.f, 0.f};
#pragma unroll
        for (int kc = 0; kc < 2; ++kc) {
            const s16x8 a = *(const s16x8*)&act[l15 * ROWP + kc * 32 + q * 8];
#pragma unroll
            for (int nt = 0; nt < 4; ++nt)
                xacc[nt] = __builtin_amdgcn_mfma_f32_16x16x32_bf16(a, bxw1[kc][nt], xacc[nt], 0, 0, 0);
        }
        // ---- phi_x layer 2 ----
        float ssum[4];
#pragma unroll
        for (int r = 0; r < 4; ++r) {
            float s = 0.f;
#pragma unroll
            for (int nt = 0; nt < 4; ++nt)
                s += silu(xacc[nt][r] + xb1v[nt]) * xw2v[nt];
            ssum[r] = s;
        }
#pragma unroll
        for (int off = 1; off < 16; off <<= 1)
#pragma unroll
            for (int r = 0; r < 4; ++r) ssum[r] += __shfl_xor(ssum[r], off, 64);
        if (l15 == 0) {
#pragma unroll
            for (int r = 0; r < 4; ++r) wv[q * 4 + r] = ssum[r] + xb2v;
        }

        // ---- segmented per-dst aggregation ----
        int dstv[17];
#pragma unroll
        for (int rr = 0; rr < 16; ++rr) dstv[rr] = __shfl(didx, rr, 64);
        dstv[16] = -1;

        float macc = 0.f;
#pragma unroll
        for (int rr = 0; rr < 16; ++rr) {
            macc += bf2f(act[rr * ROWP + lane]);
            if (dstv[rr + 1] != dstv[rr]) {
                atomicAdd(&m_agg[dstv[rr] * 64 + lane], macc);
                macc = 0.f;
            }
        }
        if (lane < 3) {
            float xac = 0.f;
#pragma unroll
            for (int rr = 0; rr < 16; ++rr) {
                xac += wv[rr] * xd[rr][lane];
                if (dstv[rr + 1] != dstv[rr]) {
                    atomicAdd(&x_agg[dstv[rr] * 3 + lane], xac);
                    xac = 0.f;
                }
            }
        }
    }
}

// -------------------------------------------------------------- node MFMA ---
// h kept bf16-only (residual in bf16); w2 in registers; fast silu.
__global__ __launch_bounds__(256, 4) void node_mfma_kernel(
    float* __restrict__ x,
    const float* __restrict__ m_agg, const float* __restrict__ x_agg,
    const float* __restrict__ w1, const float* __restrict__ b1,   // [128][64]
    const float* __restrict__ w2, const float* __restrict__ b2,   // [64][64]
    unsigned short* __restrict__ h_bf,
    void* __restrict__ outv, const int* __restrict__ flag)
{
    __shared__ unsigned short s_w1p[4 * 4 * 64 * 8];   // 16 KB
    __shared__ unsigned short s_act[4][16 * ROWP];     // 9 KB

    const int tid = threadIdx.x;
    for (int p = tid; p < 4 * 4 * 64 * 8; p += 256) {
        const int j = p & 7, ln = (p >> 3) & 63, nt = (p >> 9) & 3, kc = p >> 11;
        const int k = kc * 32 + (ln >> 4) * 8 + j, n = nt * 16 + (ln & 15);
        s_w1p[p] = f2bf(w1[k * 64 + n]);
    }
    __syncthreads();

    const int bf = flag ? *flag : 1;
    const int lane = tid & 63;
    const int wid = tid >> 6;
    const int l15 = lane & 15;
    const int q = lane >> 4;

    // x update (+ optional out)
    for (int n = blockIdx.x * 256 + tid; n < NN; n += gridDim.x * 256) {
#pragma unroll
        for (int c = 0; c < 3; ++c) {
            const float xn = x[n * 4 + c] + x_agg[n * 3 + c];
            x[n * 4 + c] = xn;
            if (outv) {
                if (bf) ((unsigned short*)outv)[NN * HD + n * 3 + c] = f2bf(xn);
                else ((float*)outv)[NN * HD + n * 3 + c] = xn;
            }
        }
    }

    s16x8 bw2[2][4];
#pragma unroll
    for (int kc = 0; kc < 2; ++kc)
#pragma unroll
        for (int nt = 0; nt < 4; ++nt)
#pragma unroll
            for (int j = 0; j < 8; ++j)
                bw2[kc][nt][j] = (short)f2bf(w2[(kc * 32 + q * 8 + j) * 64 + nt * 16 + l15]);

    float b1v[4], b2v[4];
#pragma unroll
    for (int nt = 0; nt < 4; ++nt) {
        b1v[nt] = b1[nt * 16 + l15];
        b2v[nt] = b2[nt * 16 + l15];
    }
    unsigned short* act = s_act[wid];

    for (int t = (blockIdx.x << 2) + wid; t < NT_N; t += gridDim.x << 2) {
        const int n = t * 16 + l15;
        const s16x8 a0 = *(const s16x8*)&h_bf[n * 64 + q * 8];
        const s16x8 a1 = *(const s16x8*)&h_bf[n * 64 + 32 + q * 8];
        const f32x4 m0 = *(const f32x4*)&m_agg[n * 64 + q * 8];
        const f32x4 m1 = *(const f32x4*)&m_agg[n * 64 + q * 8 + 4];
        const f32x4 m2 = *(const f32x4*)&m_agg[n * 64 + 32 + q * 8];
        const f32x4 m3 = *(const f32x4*)&m_agg[n * 64 + 32 + q * 8 + 4];
        s16x8 a2, a3;
#pragma unroll
        for (int j = 0; j < 4; ++j) {
            a2[j] = (short)f2bf(m0[j]); a2[4 + j] = (short)f2bf(m1[j]);
            a3[j] = (short)f2bf(m2[j]); a3[4 + j] = (short)f2bf(m3[j]);
        }

        f32x4 acc[4];
#pragma unroll
        for (int nt = 0; nt < 4; ++nt) acc[nt] = (f32x4){0.f, 0.f, 0.f, 0.f};
#pragma unroll
        for (int kc = 0; kc < 4; ++kc) {
            const s16x8 a = (kc == 0) ? a0 : (kc == 1) ? a1 : (kc == 2) ? a2 : a3;
#pragma unroll
            for (int nt = 0; nt < 4; ++nt) {
                const s16x8 b = *(const s16x8*)&s_w1p[((kc * 4 + nt) * 64 + lane) * 8];
                acc[nt] = __builtin_amdgcn_mfma_f32_16x16x32_bf16(a, b, acc[nt], 0, 0, 0);
            }
        }
#pragma unroll
        for (int nt = 0; nt < 4; ++nt)
#pragma unroll
            for (int r = 0; r < 4; ++r)
                act[(q * 4 + r) * ROWP + nt * 16 + l15] = f2bf_t(silu(acc[nt][r] + b1v[nt]));

        f32x4 acc2[4];
#pragma unroll
        for (int nt = 0; nt < 4; ++nt) acc2[nt] = (f32x4){0.f, 0.f, 0.f, 0.f};
#pragma unroll
        for (int kc = 0; kc < 2; ++kc) {
            const s16x8 a = *(const s16x8*)&act[l15 * ROWP + kc * 32 + q * 8];
#pragma unroll
            for (int nt = 0; nt < 4; ++nt)
                acc2[nt] = __builtin_amdgcn_mfma_f32_16x16x32_bf16(a, bw2[kc][nt], acc2[nt], 0, 0, 0);
        }
#pragma unroll
        for (int nt = 0; nt < 4; ++nt)
#pragma unroll
            for (int r = 0; r < 4; ++r) {
                const int row = t * 16 + q * 4 + r, col = nt * 16 + l15;
                const float hn = bf2f(h_bf[row * 64 + col]) + acc2[nt][r] + b2v[nt];
                h_bf[row * 64 + col] = f2bf(hn);
                if (outv) {
                    if (bf) ((unsigned short*)outv)[row * 64 + col] = f2bf(hn);
                    else ((float*)outv)[row * 64 + col] = hn;
                }
            }
    }
}

// -------------------------------------------------------------- launch ------
extern "C" void kernel_launch(void* const* d_in, const int* in_sizes, int n_in,
                              void* d_out, int out_size, void* d_ws, size_t ws_size,
                              hipStream_t stream) {
    const int* an = (const int*)d_in[0];
    const void* pos = d_in[1];
    const int* ei = (const int*)d_in[2];

    int wi = 4;
    if (n_in > 4 && in_sizes[4] == 6400) wi = 4;
    else if (n_in > 3 && in_sizes[3] == 6400) wi = 3;
    const void* emb = d_in[wi];
    const void* e_w1 = d_in[wi + 1];
    const void* e_b1 = d_in[wi + 2];
    const void* e_w2 = d_in[wi + 3];
    const void* e_b2 = d_in[wi + 4];
    const void* h_w1 = d_in[wi + 5];
    const void* h_b1 = d_in[wi + 6];
    const void* h_w2 = d_in[wi + 7];
    const void* h_b2 = d_in[wi + 8];
    const void* x_w1 = d_in[wi + 9];
    const void* x_b1 = d_in[wi + 10];
    const void* x_w2 = d_in[wi + 11];
    const void* x_b2 = d_in[wi + 12];

    float* ws = (float*)d_ws;
    int* flag = (int*)(ws + FLAG_OFF);
    float* wbuf = ws + WB_OFF;
    float* x = ws + X_OFF;
    float* m_agg = ws + MAGG_OFF;
    float* x_agg = ws + XAGG_OFF;
    unsigned short* h_bf = (unsigned short*)(ws + HBF_OFF);
    int* cnt = (int*)(ws + CNT_OFF);
    int* csum = (int*)(ws + CSUM_OFF);
    int* incl = (int*)(ws + INCL_OFF);
    int2* pair = (int2*)(ws + PAIR_OFF);

    detect_kernel<<<1, 64, 0, stream>>>((const unsigned short*)pos, flag);
    convert_kernel<<<256, 256, 0, stream>>>(pos, emb,
        e_w1, e_b1, e_w2, e_b2, h_w1, h_b1, h_w2, h_b2,
        x_w1, x_b1, x_w2, x_b2, wbuf, x, flag);
    init_h_kernel<<<784, 256, 0, stream>>>(an, wbuf + EMB_O, h_bf);

    hipMemsetAsync(cnt, 0, NCH * 256 * sizeof(int), stream);
    hist_kernel<<<512, 256, 0, stream>>>(ei, cnt);
    scan1_kernel<<<NCH, 256, 0, stream>>>(cnt, incl, csum);
    scan2_kernel<<<1, 256, 0, stream>>>(csum);
    scan3_kernel<<<NCH, 256, 0, stream>>>(cnt, incl, csum);
    scatter_kernel<<<512, 256, 0, stream>>>(ei, cnt, pair);

    for (int l = 0; l < NL; ++l) {
        hipMemsetAsync(m_agg, 0, (size_t)NN * HD * sizeof(float), stream);
        hipMemsetAsync(x_agg, 0, (size_t)NN * 3 * sizeof(float), stream);

        edge_mfma_kernel<<<1024, 256, 0, stream>>>(h_bf, x, pair,
            wbuf + EW1_O + l * 129 * 64, wbuf + EB1_O + l * 64,
            wbuf + EB2_O + l * 64,
            wbuf + EW2_O + l * 64 * 64,
            wbuf + XW1_O + l * 64 * 64, wbuf + XB1_O + l * 64,
            wbuf + XW2_O + l * 64, wbuf + XB2_O + l,
            m_agg, x_agg);

        void* out_p = (l == NL - 1) ? d_out : nullptr;
        node_mfma_kernel<<<782, 256, 0, stream>>>(x, m_agg, x_agg,
            wbuf + HW1_O + l * 128 * 64, wbuf + HB1_O + l * 64,
            wbuf + HW2_O + l * 64 * 64, wbuf + HB2_O + l * 64,
            h_bf, out_p, flag);
    }
}